// Round 6
// baseline (310.878 us; speedup 1.0000x reference)
//
#include <hip/hip_runtime.h>
#include <math.h>

// B=64, Q=4096, N=256, 20 fg classes + 1 bg. Output (B,Q,N) fp32 = 268 MB.
// KEY SPARSITY FACT: centers uniform in [0,50]^3, gate radius 2.0 ->
// P(pair active) ~ 0.027%; P(q-row of 256 has any active) ~ 6.6%.
//
// Ledger: R0 fused+staged softmax = 294.9 (matcher ~114us, storeless ~91us
// per R1 A/B -> stores overlapped). R2-R4 softmax-in-slow-path +
// launch_bounds(256,6) = 314.8 (spills; reverted). R5 4-row ILP = 297.5
// (null -> not chain-latency-bound; work count is the lever).
// R6: conservative 50^3 voxel mask (cell=1.0) kills the d2 loop for ~84%
// of rows: one bit per q decides "row cannot contain any active pair" ->
// store MISS row immediately. Mask is dilated by box-distance <= 2 with
// margin (4.05 > gate 4.0000005), so zero false negatives = bit-exact.
#define BQ 64
#define QQ 4096
#define NN 256
#define NC 20
#define NL 21
#define TQ 256          // queries per block
#define GEO_STRIDE 12   // 10 floats used + 2 pad -> 48 B, 16-B aligned (ds_read_b128)
#define PROB_STRIDE 257 // label gather hits distinct banks; staging writes conflict-free

// Gate: sqrt_rn(d2) <= 2.0  <=>  d2 <= 4 + ulp(4)  (bit-exact vs numpy fp32).
#define GATE_D2 0x1.000001p+2f

// Voxel mask: 50x50x50 cells of 1.0 unit -> 125000 bits per batch b.
#define MCELLS 50
#define MWORDS 3907     // ceil(125000/32)
#define MSTRIDE 3920    // padded words per b (16-B aligned rows)
#define MMARGIN 4.05f   // conservative d2 threshold for cell dilation

__global__ __launch_bounds__(256)
void mask_kernel(const float* __restrict__ tboxes, unsigned* __restrict__ gmask) {
    __shared__ unsigned sm[MWORDS];     // 15.6 KB
    const int tid = threadIdx.x;
    const int b   = blockIdx.x;
    for (int i = tid; i < MWORDS; i += 256) sm[i] = 0u;
    __syncthreads();

    // one target per thread (NN == 256 == blockDim)
    const float* tb = tboxes + (size_t)(b * NN + tid) * 6;
    const float tx = tb[0], ty = tb[1], tz = tb[2];
    int x0 = (int)floorf(tx - 2.f); x0 = x0 < 0 ? 0 : x0;
    int x1 = (int)floorf(tx + 2.f); x1 = x1 > MCELLS - 1 ? MCELLS - 1 : x1;
    int y0 = (int)floorf(ty - 2.f); y0 = y0 < 0 ? 0 : y0;
    int y1 = (int)floorf(ty + 2.f); y1 = y1 > MCELLS - 1 ? MCELLS - 1 : y1;
    int z0 = (int)floorf(tz - 2.f); z0 = z0 < 0 ? 0 : z0;
    int z1 = (int)floorf(tz + 2.f); z1 = z1 > MCELLS - 1 ? MCELLS - 1 : z1;

    #pragma unroll 1
    for (int i = x0; i <= x1; ++i) {
        const float dx = fmaxf(fmaxf((float)i - tx, tx - (float)(i + 1)), 0.f);
        #pragma unroll 1
        for (int j = y0; j <= y1; ++j) {
            const float dy = fmaxf(fmaxf((float)j - ty, ty - (float)(j + 1)), 0.f);
            #pragma unroll 1
            for (int k = z0; k <= z1; ++k) {
                const float dz = fmaxf(fmaxf((float)k - tz, tz - (float)(k + 1)), 0.f);
                const float d2 = dx * dx + dy * dy + dz * dz;
                if (d2 <= MMARGIN) {   // cell box within gate reach of target
                    const int idx = (i * MCELLS + j) * MCELLS + k;
                    atomicOr(&sm[idx >> 5], 1u << (idx & 31));
                }
            }
        }
    }
    __syncthreads();
    unsigned* gb = gmask + (size_t)b * MSTRIDE;
    for (int i = tid; i < MWORDS; i += 256) gb[i] = sm[i];
}

__global__ __launch_bounds__(256)
void matcher_kernel(const float* __restrict__ logits,
                    const float* __restrict__ pboxes,
                    const int*   __restrict__ tlabels,
                    const float* __restrict__ tboxes,
                    const unsigned* __restrict__ gmask,   // may be null (no mask)
                    float* __restrict__ out) {
    __shared__ __align__(16) float geo[TQ * GEO_STRIDE];    // 12 KB
    __shared__ float prob[NC * PROB_STRIDE];                // 20.1 KB
    __shared__ int actq[TQ];                                // 1 KB
    const int tid = threadIdx.x;
    const int b   = blockIdx.y;
    const int q0  = blockIdx.x * TQ;

    // ---- staging: one q per thread (softmax once per q) ----
    {
        const int q = q0 + tid;
        const float* lg = logits + (size_t)(b * QQ + q) * NL;
        float l[NL];
        #pragma unroll
        for (int c = 0; c < NL; ++c) l[c] = lg[c];
        float m = l[0];
        #pragma unroll
        for (int c = 1; c < NL; ++c) m = fmaxf(m, l[c]);
        float e[NL];
        float s = 0.f;
        #pragma unroll
        for (int c = 0; c < NL; ++c) { e[c] = expf(l[c] - m); s += e[c]; }
        const float rs = 1.0f / s;
        #pragma unroll
        for (int c = 0; c < NC; ++c)    // bank (c+tid)%32 -> 2 lanes/bank (free)
            prob[c * PROB_STRIDE + tid] = -(e[c] * rs);

        const float* pb = pboxes + (size_t)(b * QQ + q) * 6;
        const float pcx = pb[0], pcy = pb[1], pcz = pb[2];
        const float psx = pb[3], psy = pb[4], psz = pb[5];
        float4* gp = (float4*)(geo + tid * GEO_STRIDE);
        gp[0] = make_float4(pcx, pcy, pcz, psx * psy * psz);
        gp[1] = make_float4(pcx - psx * 0.5f, pcy - psy * 0.5f, pcz - psz * 0.5f, 0.f);
        gp[2] = make_float4(pcx + psx * 0.5f, pcy + psy * 0.5f, pcz + psz * 0.5f, 0.f);

        // ---- row-activity bit from the voxel mask (1 global load per q) ----
        int flag = 1;
        if (gmask) {
            int cx = (int)pcx; cx = cx > MCELLS - 1 ? MCELLS - 1 : cx;
            int cy = (int)pcy; cy = cy > MCELLS - 1 ? MCELLS - 1 : cy;
            int cz = (int)pcz; cz = cz > MCELLS - 1 ? MCELLS - 1 : cz;
            const int idx = (cx * MCELLS + cy) * MCELLS + cz;
            flag = (int)((gmask[(size_t)b * MSTRIDE + (idx >> 5)] >> (idx & 31)) & 1u);
        }
        actq[tid] = flag;
    }

    // ---- per-thread: quad of targets n0..n0+3 in registers ----
    const int lane = tid & 63;
    const int w    = tid >> 6;
    const int n0   = lane * 4;
    float tcx[4], tcy[4], tcz[4];
    float mn_x[4], mn_y[4], mn_z[4], mx_x[4], mx_y[4], mx_z[4], v2[4];
    int plab[4];
    #pragma unroll
    for (int j = 0; j < 4; ++j) {
        const float* tb = tboxes + (size_t)(b * NN + n0 + j) * 6;
        const float cx = tb[0], cy = tb[1], cz = tb[2];
        const float sx = tb[3], sy = tb[4], sz = tb[5];
        tcx[j] = cx; tcy[j] = cy; tcz[j] = cz;
        mn_x[j] = cx - sx * 0.5f; mn_y[j] = cy - sy * 0.5f; mn_z[j] = cz - sz * 0.5f;
        mx_x[j] = cx + sx * 0.5f; mx_y[j] = cy + sy * 0.5f; mx_z[j] = cz + sz * 0.5f;
        v2[j]   = sx * sy * sz;
        plab[j] = tlabels[b * NN + n0 + j] * PROB_STRIDE;
    }

    __syncthreads();

    const float4 MISS = make_float4(1000000.0f, 1000000.0f, 1000000.0f, 1000000.0f);
    float* ob = out + ((size_t)(b * QQ + q0)) * NN + n0;

    // Each wave handles qq = w, w+4, ... One dwordx4 store per wave-iter
    // covers a contiguous 1-KB q-row (coalesced).
    // Fast path now: ONE uniform LDS bit -> store MISS. ~84% of rows.
    #pragma unroll 1
    for (int qq = w; qq < TQ; qq += 4) {
        float4* orow = (float4*)(ob + (size_t)qq * NN);

        if (actq[qq] == 0) {           // wave-uniform; conservative => exact
            *orow = MISS;
            continue;
        }

        const float4* gp = (const float4*)(geo + qq * GEO_STRIDE); // uniform broadcast
        const float4 g0 = gp[0];   // pc.xyz, vol1

        // strict fp32, numpy op order, no FMA: feeds the 1e6 discontinuity gate
        float d2v[4];
        int active = 0;
        #pragma unroll
        for (int j = 0; j < 4; ++j) {
            const float dx = __fsub_rn(g0.x, tcx[j]);
            const float dy = __fsub_rn(g0.y, tcy[j]);
            const float dz = __fsub_rn(g0.z, tcz[j]);
            d2v[j] = __fadd_rn(__fadd_rn(__fmul_rn(dx, dx), __fmul_rn(dy, dy)),
                               __fmul_rn(dz, dz));
            active |= (d2v[j] <= GATE_D2);
        }

        if (!__any(active)) {          // mask false-positive row: all miss
            *orow = MISS;
            continue;
        }

        const float4 g1 = gp[1];       // min1.xyz
        const float4 g2 = gp[2];       // max1.xyz
        float r[4];
        #pragma unroll
        for (int j = 0; j < 4; ++j) {
            const float negp = prob[plab[j] + qq];

            const float dist = __builtin_amdgcn_sqrtf(d2v[j]); // continuous term only

            const float ix = fmaxf(fminf(g2.x, mx_x[j]) - fmaxf(g1.x, mn_x[j]), 0.f);
            const float iy = fmaxf(fminf(g2.y, mx_y[j]) - fmaxf(g1.y, mn_y[j]), 0.f);
            const float iz = fmaxf(fminf(g2.z, mx_z[j]) - fmaxf(g1.z, mn_z[j]), 0.f);
            const float iv  = ix * iy * iz;
            const float uni = g0.w + v2[j] - iv;     // > 0 always (sizes >= 0.5)
            const float iou = iv * __builtin_amdgcn_rcpf(uni);

            const float t = fmaf(5.0f, dist, negp) + fmaf(-2.0f, iou, 2.0f);
            r[j] = (d2v[j] <= GATE_D2) ? t : 1000000.0f;   // bit-exact gate
        }
        *orow = make_float4(r[0], r[1], r[2], r[3]);
    }
}

extern "C" void kernel_launch(void* const* d_in, const int* in_sizes, int n_in,
                              void* d_out, int out_size, void* d_ws, size_t ws_size,
                              hipStream_t stream) {
    const float* logits  = (const float*)d_in[0];  // (B,Q,21)
    const float* pboxes  = (const float*)d_in[1];  // (B,Q,6)
    const int*   tlabels = (const int*)d_in[2];    // (B,N)
    const float* tboxes  = (const float*)d_in[3];  // (B,N,6)
    float* out = (float*)d_out;                    // (B,Q,N) fp32

    unsigned* gmask = nullptr;
    if (ws_size >= (size_t)BQ * MSTRIDE * sizeof(unsigned)) {   // ~1.0 MB
        gmask = (unsigned*)d_ws;
        mask_kernel<<<dim3(BQ), dim3(256), 0, stream>>>(tboxes, gmask);
    }

    dim3 grid(QQ / TQ, BQ);                        // 16 x 64 = 1024 blocks = 4/CU
    matcher_kernel<<<grid, dim3(256), 0, stream>>>(logits, pboxes, tlabels, tboxes,
                                                   gmask, out);
}

// Round 7
// 295.651 us; speedup vs baseline: 1.0515x; 1.0515x over previous
//
#include <hip/hip_runtime.h>
#include <math.h>

// B=64, Q=4096, N=256, 20 fg classes + 1 bg. Output (B,Q,N) fp32 = 268 MB.
// KEY SPARSITY FACT: centers uniform in [0,50]^3, gate radius 2.0 ->
// P(pair active) ~ 0.027%; P(q-row of 256 has any active) ~ 6.6%.
//
// Ledger: R0 fused+staged = 294.9 (best). R1 split fill/storeless = 315.5
// (stores bounded <=20us). R2-R4 launch_bounds(256,6) = 314.8 (VGPR spills;
// never cap VGPRs here). R5 4-row ILP = 297.5 (null). R6 voxel mask
// (-84% d2 work) = 310.9 (negative -> issue count is not the limiter).
// Per-wave store throughput matcher~=fill (0.55 vs 0.72 GB/s/wave) ->
// aggregate tracks WAVE COUNT. R7: +25% waves via LDS shave:
// prob q-major [256][20] -> LDS = 12288+20480 = 32768 B exactly
// -> 5 blocks/CU (20 waves) vs 4 (16). No VGPR cap. Loop math verbatim R0.
// Also: contiguous 64-row span per wave, 4-row batches off one base addr
// (stores become offset:0/1024/2048/3072 off a shared base).
#define BQ 64
#define QQ 4096
#define NN 256
#define NC 20
#define NL 21
#define TQ 256          // queries per block
#define GEO_STRIDE 12   // 10 floats used + 2 pad -> 48 B, 16-B aligned (ds_read_b128)
#define PSTR 20         // q-major prob row: [TQ][PSTR], gather qq*20+lab is
                        // 20 distinct banks + same-address broadcast -> ~free

// Gate: sqrt_rn(d2) <= 2.0  <=>  d2 <= 4 + ulp(4)  (bit-exact vs numpy fp32).
#define GATE_D2 0x1.000001p+2f

__global__ __launch_bounds__(256)
void matcher_kernel(const float* __restrict__ logits,
                    const float* __restrict__ pboxes,
                    const int*   __restrict__ tlabels,
                    const float* __restrict__ tboxes,
                    float* __restrict__ out) {
    __shared__ __align__(16) float geo[TQ * GEO_STRIDE];    // 12288 B
    __shared__ float prob[TQ * PSTR];                       // 20480 B -> 32768 total
    const int tid = threadIdx.x;
    const int b   = blockIdx.y;
    const int q0  = blockIdx.x * TQ;

    // ---- staging: one q per thread (softmax once per q) ----
    {
        const int q = q0 + tid;
        const float* lg = logits + (size_t)(b * QQ + q) * NL;
        float l[NL];
        #pragma unroll
        for (int c = 0; c < NL; ++c) l[c] = lg[c];
        float m = l[0];
        #pragma unroll
        for (int c = 1; c < NL; ++c) m = fmaxf(m, l[c]);
        float e[NL];
        float s = 0.f;
        #pragma unroll
        for (int c = 0; c < NL; ++c) { e[c] = expf(l[c] - m); s += e[c]; }
        const float rs = 1.0f / s;
        #pragma unroll
        for (int c = 0; c < NC; ++c)    // 8-way bank conflict, but once per block
            prob[tid * PSTR + c] = -(e[c] * rs);

        const float* pb = pboxes + (size_t)(b * QQ + q) * 6;
        const float pcx = pb[0], pcy = pb[1], pcz = pb[2];
        const float psx = pb[3], psy = pb[4], psz = pb[5];
        float4* gp = (float4*)(geo + tid * GEO_STRIDE);
        gp[0] = make_float4(pcx, pcy, pcz, psx * psy * psz);
        gp[1] = make_float4(pcx - psx * 0.5f, pcy - psy * 0.5f, pcz - psz * 0.5f, 0.f);
        gp[2] = make_float4(pcx + psx * 0.5f, pcy + psy * 0.5f, pcz + psz * 0.5f, 0.f);
    }

    // ---- per-thread: quad of targets n0..n0+3 in registers ----
    const int lane = tid & 63;
    const int w    = tid >> 6;
    const int n0   = lane * 4;
    float tcx[4], tcy[4], tcz[4];
    float mn_x[4], mn_y[4], mn_z[4], mx_x[4], mx_y[4], mx_z[4], v2[4];
    int lab[4];
    #pragma unroll
    for (int j = 0; j < 4; ++j) {
        const float* tb = tboxes + (size_t)(b * NN + n0 + j) * 6;
        const float cx = tb[0], cy = tb[1], cz = tb[2];
        const float sx = tb[3], sy = tb[4], sz = tb[5];
        tcx[j] = cx; tcy[j] = cy; tcz[j] = cz;
        mn_x[j] = cx - sx * 0.5f; mn_y[j] = cy - sy * 0.5f; mn_z[j] = cz - sz * 0.5f;
        mx_x[j] = cx + sx * 0.5f; mx_y[j] = cy + sy * 0.5f; mx_z[j] = cz + sz * 0.5f;
        v2[j]   = sx * sy * sz;
        lab[j]  = tlabels[b * NN + n0 + j];
    }

    __syncthreads();

    const float4 MISS = make_float4(1000000.0f, 1000000.0f, 1000000.0f, 1000000.0f);

    // Wave w owns contiguous rows [w*64, w*64+64): a 64-KB output stream.
    // 4-row batches share one base address; stores land at imm offsets
    // 0/1024/2048/3072. Fast path: d2 + gate only (verbatim R0 math).
    const int r0 = w * 64;
    char* wbase = (char*)(out + ((size_t)(b * QQ + q0 + r0)) * NN + n0);

    #pragma unroll 1
    for (int k = 0; k < 64; k += 4) {
        const int qq = r0 + k;
        char* base = wbase + (size_t)k * (NN * 4);

        float4 g0[4];
        #pragma unroll
        for (int rr = 0; rr < 4; ++rr)
            g0[rr] = ((const float4*)(geo + (qq + rr) * GEO_STRIDE))[0]; // pc.xyz, vol1

        // strict fp32, numpy op order, no FMA: feeds the 1e6 discontinuity gate
        float d2v[4][4];
        int act = 0;
        #pragma unroll
        for (int rr = 0; rr < 4; ++rr) {
            #pragma unroll
            for (int j = 0; j < 4; ++j) {
                const float dx = __fsub_rn(g0[rr].x, tcx[j]);
                const float dy = __fsub_rn(g0[rr].y, tcy[j]);
                const float dz = __fsub_rn(g0[rr].z, tcz[j]);
                d2v[rr][j] = __fadd_rn(__fadd_rn(__fmul_rn(dx, dx), __fmul_rn(dy, dy)),
                                       __fmul_rn(dz, dz));
                act |= (d2v[rr][j] <= GATE_D2) << rr;
            }
        }

        if (!__any(act)) {             // ~76% of batches: 4 MISS rows, one base
            #pragma unroll
            for (int rr = 0; rr < 4; ++rr)
                *(float4*)(base + rr * 1024) = MISS;
            continue;
        }

        #pragma unroll
        for (int rr = 0; rr < 4; ++rr) {
            float4* orow = (float4*)(base + rr * 1024);
            if (!__any((act >> rr) & 1)) {   // this row all-miss
                *orow = MISS;
                continue;
            }
            // ---- slow path: verbatim R0 per-row compute (bit-exact) ----
            const float4* gp = (const float4*)(geo + (qq + rr) * GEO_STRIDE);
            const float4 g1 = gp[1];   // min1.xyz
            const float4 g2 = gp[2];   // max1.xyz
            float r[4];
            #pragma unroll
            for (int j = 0; j < 4; ++j) {
                const float negp = prob[(qq + rr) * PSTR + lab[j]];

                const float dist = __builtin_amdgcn_sqrtf(d2v[rr][j]);

                const float ix = fmaxf(fminf(g2.x, mx_x[j]) - fmaxf(g1.x, mn_x[j]), 0.f);
                const float iy = fmaxf(fminf(g2.y, mx_y[j]) - fmaxf(g1.y, mn_y[j]), 0.f);
                const float iz = fmaxf(fminf(g2.z, mx_z[j]) - fmaxf(g1.z, mn_z[j]), 0.f);
                const float iv  = ix * iy * iz;
                const float uni = g0[rr].w + v2[j] - iv;   // > 0 always (sizes >= 0.5)
                const float iou = iv * __builtin_amdgcn_rcpf(uni);

                const float t = fmaf(5.0f, dist, negp) + fmaf(-2.0f, iou, 2.0f);
                r[j] = (d2v[rr][j] <= GATE_D2) ? t : 1000000.0f;   // bit-exact gate
            }
            *orow = make_float4(r[0], r[1], r[2], r[3]);
        }
    }
}

extern "C" void kernel_launch(void* const* d_in, const int* in_sizes, int n_in,
                              void* d_out, int out_size, void* d_ws, size_t ws_size,
                              hipStream_t stream) {
    const float* logits  = (const float*)d_in[0];  // (B,Q,21)
    const float* pboxes  = (const float*)d_in[1];  // (B,Q,6)
    const int*   tlabels = (const int*)d_in[2];    // (B,N)
    const float* tboxes  = (const float*)d_in[3];  // (B,N,6)
    float* out = (float*)d_out;                    // (B,Q,N) fp32

    dim3 grid(QQ / TQ, BQ);                        // 16 x 64 = 1024 blocks, 5/CU now
    matcher_kernel<<<grid, dim3(256), 0, stream>>>(logits, pboxes, tlabels, tboxes, out);
}